// Round 1
// 301.994 us; speedup vs baseline: 1.0147x; 1.0147x over previous
//
#include <hip/hip_runtime.h>
#include <hip/hip_bf16.h>

// Problem constants
#define S_LEN 2048
#define HID   4096
#define NH    32
#define NKV   8
#define DH    128
#define NQKV  ((NH + 2*NKV) * DH)   // 6144

typedef __attribute__((ext_vector_type(8))) short s16x8;
typedef __attribute__((ext_vector_type(4))) short s16x4;
typedef __attribute__((ext_vector_type(4))) float f32x4;

__device__ __forceinline__ short f2bf(float x) {
    union { __hip_bfloat16 b; short s; } u;
    u.b = __float2bfloat16(x);
    return u.s;
}
__device__ __forceinline__ float bf2f(short s) {
    union { unsigned int u; float f; } v;
    v.u = ((unsigned int)(unsigned short)s) << 16;
    return v.f;
}

// async global->LDS, 16B per lane; lds dest = wave-uniform base + lane*16
__device__ __forceinline__ void gload16(const void* g, void* l) {
    __builtin_amdgcn_global_load_lds(
        (const __attribute__((address_space(1))) void*)g,
        (__attribute__((address_space(3))) void*)l,
        16, 0, 0);
}

__device__ __forceinline__ void cstore(float* p, float v) { *p = v; }
__device__ __forceinline__ void cstore(short* p, float v) { *p = f2bf(v); }

// ---------------------------------------------------------------------------
// fused f32 -> bf16 conversion of hs AND wqkv in one launch
// ---------------------------------------------------------------------------
__global__ __launch_bounds__(256) void convert_hs_wqkv(
        const float* __restrict__ in1, short* __restrict__ o1, long n1,
        const float* __restrict__ in2, short* __restrict__ o2, long n2)
{
    const long total = n1 + n2;
    long i0 = ((long)blockIdx.x * blockDim.x + threadIdx.x) * 4;
    long stride = (long)gridDim.x * blockDim.x * 4;
    for (long i = i0; i < total; i += stride) {
        const float* src; short* dst; long off;
        if (i < n1) { src = in1; dst = o1; off = i; }
        else        { src = in2; dst = o2; off = i - n1; }
        float4 v = *(const float4*)(src + off);
        s16x4 o;
        o[0] = f2bf(v.x); o[1] = f2bf(v.y); o[2] = f2bf(v.z); o[3] = f2bf(v.w);
        *(s16x4*)(dst + off) = o;
    }
}

// ---------------------------------------------------------------------------
// 256x192-tile bf16 GEMM, C = A * B^T.  Round-1 rework: software-pipelined
// LDS reads (read-ahead one 24-MFMA batch), counted lgkmcnt, 2 barriers per
// K-tile (was 6).  Reads now overlap MFMA instead of serializing with it.
//   per K-tile/wave: 48 MFMA in two batches M0 = a-quad0 x B, M1 = a-quad1 x B
//   R0 = {a-quad0 + all B} (14 ds_read_b128) issued at END of prev tile
//   R1 = {a-quad1}        (8 ds_read_b128)  issued at top, drained by
//        lgkmcnt(8) -> M0 runs while R1 completes.
//   barrier#1 after lgkmcnt(0): slot(t) reads done -> stage(t+2) safe.
//   barrier#2 after vmcnt(7):   tile t+1 resident -> read-ahead safe.
// B-frags double-buffered (bfE/bfO) with STATIC selection via 2x-unrolled
// body (NT=64 even).  Grid 32x8 = 256 blocks = 1/CU.
// ---------------------------------------------------------------------------
template <typename OT>
__global__ __launch_bounds__(512, 2) void gemm192(
        const short* __restrict__ A, const short* __restrict__ B,
        OT* __restrict__ C, int M, int N, int K)
{
    __shared__ char lds[114688];   // A: [0,64K) 4 slots; B: [64K,112K) 2 slots
    const int t = threadIdx.x;
    const int w = t >> 6, l = t & 63, g = l >> 4, q16 = l & 15;
    const int wm = w >> 2, wn = w & 3;       // wave grid 2(M) x 4(N)
    const int bx = blockIdx.x, by = blockIdx.y;
    const int NT = K >> 6;                   // 64 (even) at K=4096

    // A staging source (chunk pre-swizzled; row&7 uniform across halves)
    const int r0 = t >> 3, c0 = t & 7;
    const int scA = c0 ^ (r0 & 7);
    const long KB64  = (long)K * 128;        // 64 rows * K * 2B
    const long KB128 = (long)K * 256;
    const long gA00 = ((long)(by * 256 + r0) * K) * 2 + scA * 16;
    // B staging source: whole 192x64 tile in 3 rounds of 8KB
    long gBoff[3];
#pragma unroll
    for (int i = 0; i < 3; ++i) {
        int row = (i * 512 + t) >> 3;        // 0..191
        int chunk = (t & 7) ^ (row & 7);
        gBoff[i] = ((long)(bx * 192 + row) * K) * 2 + chunk * 16;
    }
    const int dstw = w * 1024;               // wave-uniform LDS dest part

    auto SA = [&](int kt, int h) {           // stage A half (128 rows, 2 loads)
        char* d = lds + ((kt & 1) * 2 + h) * 16384 + dstw;
        const long s0 = gA00 + h * KB128 + (long)kt * 128;
        gload16((const char*)A + s0, d);
        gload16((const char*)A + s0 + KB64, d + 8192);
    };
    auto SB = [&](int kt) {                  // stage whole B tile (3 loads)
        char* d = lds + 65536 + (kt & 1) * 24576 + dstw;
        const long kb = (long)kt * 128;
#pragma unroll
        for (int i = 0; i < 3; ++i)
            gload16((const char*)B + gBoff[i] + kb, d + i * 8192);
    };

    // LDS read offsets: row&7 == q16&7 everywhere (48,16,64,128 mult of 8)
    const int arow = q16 * 128;
    const int brow = (wn * 48 + q16) * 128;
    const int sw0 = ((g) ^ (q16 & 7)) << 4;
    const int sw1 = ((4 + g) ^ (q16 & 7)) << 4;

    f32x4 acc[8][3] = {};
    s16x8 a0f[4][2], a1f[4][2], bfE[3][2], bfO[3][2];

    // prologue: tile0 (7 loads), tile1 (7 loads); drain tile0
    SB(0); SA(0, 0); SA(0, 1);
    SB(1); SA(1, 0); SA(1, 1);
    asm volatile("s_waitcnt vmcnt(7)" ::: "memory");
    __builtin_amdgcn_s_barrier();
    asm volatile("" ::: "memory");
    {   // read-ahead R0(0): a-quad0 + all B of tile 0 (slot parity 0 -> bfE)
        const char* As_ = lds + wm * 16384;
        const char* Bs_ = lds + 65536;
#pragma unroll
        for (int mi = 0; mi < 4; ++mi) {
            a0f[mi][0] = *(const s16x8*)(As_ + arow + mi*2048 + sw0);
            a0f[mi][1] = *(const s16x8*)(As_ + arow + mi*2048 + sw1);
        }
#pragma unroll
        for (int ni = 0; ni < 3; ++ni) {
            bfE[ni][0] = *(const s16x8*)(Bs_ + brow + ni*2048 + sw0);
            bfE[ni][1] = *(const s16x8*)(Bs_ + brow + ni*2048 + sw1);
        }
    }

#define GBODY(KT, BCUR, BNXT, PAR) do {                                       \
    const char* As_ = lds + ((PAR)*2 + wm) * 16384;                           \
    /* R1: a-quad1 of tile t (8 ds_read_b128) */                              \
    _Pragma("unroll")                                                         \
    for (int mi = 0; mi < 4; ++mi) {                                          \
        a1f[mi][0] = *(const s16x8*)(As_ + arow + 8192 + mi*2048 + sw0);      \
        a1f[mi][1] = *(const s16x8*)(As_ + arow + 8192 + mi*2048 + sw1);      \
    }                                                                         \
    asm volatile("s_waitcnt lgkmcnt(8)" ::: "memory");  /* R0(t) done */      \
    __builtin_amdgcn_sched_barrier(0);                                        \
    __builtin_amdgcn_s_setprio(1);                                            \
    _Pragma("unroll")                                                         \
    for (int mi = 0; mi < 4; ++mi)                                            \
    _Pragma("unroll")                                                         \
    for (int ni = 0; ni < 3; ++ni)                                            \
    _Pragma("unroll")                                                         \
    for (int kk = 0; kk < 2; ++kk)                                            \
        acc[mi][ni] = __builtin_amdgcn_mfma_f32_16x16x32_bf16(                \
                a0f[mi][kk], BCUR[ni][kk], acc[mi][ni], 0, 0, 0);             \
    __builtin_amdgcn_s_setprio(0);                                            \
    asm volatile("s_waitcnt lgkmcnt(0)" ::: "memory");  /* R1(t) done */      \
    __builtin_amdgcn_sched_barrier(0);                                        \
    __builtin_amdgcn_s_barrier();       /* all waves' slot(t) reads done */   \
    if ((KT) + 2 < NT) {                                                      \
        SB((KT) + 2); SA((KT) + 2, 0); SA((KT) + 2, 1);                       \
        asm volatile("s_waitcnt vmcnt(7)" ::: "memory");  /* t+1 arrived */   \
    } else {                                                                  \
        asm volatile("s_waitcnt vmcnt(0)" ::: "memory");                      \
    }                                                                         \
    __builtin_amdgcn_s_barrier();       /* t+1 visible to all waves */        \
    asm volatile("" ::: "memory");                                            \
    if ((KT) + 1 < NT) {                /* read-ahead R0(t+1), 14 reads */    \
        const char* An_ = lds + (((PAR) ^ 1) * 2 + wm) * 16384;               \
        const char* Bn_ = lds + 65536 + ((PAR) ^ 1) * 24576;                  \
        _Pragma("unroll")                                                     \
        for (int mi = 0; mi < 4; ++mi) {                                      \
            a0f[mi][0] = *(const s16x8*)(An_ + arow + mi*2048 + sw0);         \
            a0f[mi][1] = *(const s16x8*)(An_ + arow + mi*2048 + sw1);         \
        }                                                                     \
        _Pragma("unroll")                                                     \
        for (int ni = 0; ni < 3; ++ni) {                                      \
            BNXT[ni][0] = *(const s16x8*)(Bn_ + brow + ni*2048 + sw0);        \
            BNXT[ni][1] = *(const s16x8*)(Bn_ + brow + ni*2048 + sw1);        \
        }                                                                     \
    }                                                                         \
    __builtin_amdgcn_s_setprio(1);      /* M1 overlaps R0(t+1) in flight */   \
    _Pragma("unroll")                                                         \
    for (int mi = 0; mi < 4; ++mi)                                            \
    _Pragma("unroll")                                                         \
    for (int ni = 0; ni < 3; ++ni)                                            \
    _Pragma("unroll")                                                         \
    for (int kk = 0; kk < 2; ++kk)                                            \
        acc[4+mi][ni] = __builtin_amdgcn_mfma_f32_16x16x32_bf16(              \
                a1f[mi][kk], BCUR[ni][kk], acc[4+mi][ni], 0, 0, 0);           \
    __builtin_amdgcn_s_setprio(0);                                            \
} while (0)

    for (int kt = 0; kt < NT; kt += 2) {
        GBODY(kt,     bfE, bfO, 0);
        GBODY(kt + 1, bfO, bfE, 1);
    }
#undef GBODY

    // epilogue: D col = lane&15, row = (lane>>4)*4 + r
#pragma unroll
    for (int mf = 0; mf < 8; ++mf) {
        long row = (long)by * 256 + wm * 128 + mf * 16 + g * 4;
#pragma unroll
        for (int nf = 0; nf < 3; ++nf) {
            long col = (long)bx * 192 + wn * 48 + nf * 16 + q16;
            f32x4 v = acc[mf][nf];
#pragma unroll
            for (int r = 0; r < 4; ++r)
                cstore(&C[(row + r) * (long)N + col], v[r]);
        }
    }
}

// ---------------------------------------------------------------------------
// bf16 GEMM (2-phase, proven 920 TF), C[M][N] = A[M][K] * B[N][K]^T.
// 128x128 tile, BK=64, 512 threads (8 waves, 2Mx4N), 64x32 per wave.
// 2-D grid. Used for gemm2 (32x16 = 512 blocks = 2/CU).
// ---------------------------------------------------------------------------
template <typename OT>
__global__ __launch_bounds__(512, 4) void gemm_bt(
        const short* __restrict__ A, const short* __restrict__ B,
        OT* __restrict__ C, int M, int N, int K)
{
    __shared__ char lds[64 * 1024];
    // A bufs: [0,16K) [16K,32K); B bufs: [32K,48K) [48K,64K)
    const int t = threadIdx.x;
    const int w = t >> 6, l = t & 63, g = l >> 4, q16 = l & 15;
    const int wm = w >> 2, wn = w & 3;     // wave grid 2 (M) x 4 (N)
    const long rowA = (long)blockIdx.y * 128;
    const long rowB = (long)blockIdx.x * 128;
    const int NT = K >> 6;

    // precomputed global byte offsets for staging (chunk pre-swizzled)
    long goffA[2], goffB[2];
#pragma unroll
    for (int i = 0; i < 2; ++i) {
        int li = i * 512 + t;
        int row = li >> 3;                       // 0..127
        int chunk = (t & 7) ^ (row & 7);         // swizzled 16B chunk in row
        goffA[i] = ((rowA + row) * (long)K) * 2 + chunk * 16;
        goffB[i] = ((rowB + row) * (long)K) * 2 + chunk * 16;
    }
    const int ldsoff = w * 1024;                 // wave-uniform dest base part

    // precomputed LDS read offsets (swizzled)
    int aoff[4][2], boff[2][2];
#pragma unroll
    for (int m = 0; m < 4; ++m)
#pragma unroll
        for (int k = 0; k < 2; ++k) {
            int row = wm * 64 + m * 16 + q16;
            int chunk = (k * 4 + g) ^ (row & 7);
            aoff[m][k] = row * 128 + chunk * 16;
        }
#pragma unroll
    for (int n = 0; n < 2; ++n)
#pragma unroll
        for (int k = 0; k < 2; ++k) {
            int row = wn * 32 + n * 16 + q16;
            int chunk = (k * 4 + g) ^ (row & 7);
            boff[n][k] = row * 128 + chunk * 16;
        }

    auto STAGE = [&](int kt, char* dA, char* dB) {
        const long kb = (long)kt * 128;          // kt*64 elems * 2B
#pragma unroll
        for (int i = 0; i < 2; ++i)
            gload16((const char*)A + goffA[i] + kb, dA + i * 8192 + ldsoff);
#pragma unroll
        for (int i = 0; i < 2; ++i)
            gload16((const char*)B + goffB[i] + kb, dB + i * 8192 + ldsoff);
    };

    f32x4 acc[4][2] = {};

    STAGE(0, lds, lds + 32768);
    STAGE(1, lds + 16384, lds + 49152);

    for (int kt = 0; kt < NT; ++kt) {
        const int b = kt & 1;
        char* bA = lds + (b ? 16384 : 0);
        char* bB = lds + (b ? 49152 : 32768);
        // tile kt's 4 loads are the oldest; tile kt+1's 4 may stay in flight
        if (kt + 1 < NT) asm volatile("s_waitcnt vmcnt(4)" ::: "memory");
        else             asm volatile("s_waitcnt vmcnt(0)" ::: "memory");
        __builtin_amdgcn_s_barrier();

        s16x8 af[4][2], bfr[2][2];
#pragma unroll
        for (int m = 0; m < 4; ++m)
#pragma unroll
            for (int k = 0; k < 2; ++k)
                af[m][k] = *(const s16x8*)(bA + aoff[m][k]);
#pragma unroll
        for (int n = 0; n < 2; ++n)
#pragma unroll
            for (int k = 0; k < 2; ++k)
                bfr[n][k] = *(const s16x8*)(bB + boff[n][k]);

        __builtin_amdgcn_s_setprio(1);
#pragma unroll
        for (int m = 0; m < 4; ++m)
#pragma unroll
            for (int n = 0; n < 2; ++n)
#pragma unroll
                for (int k = 0; k < 2; ++k)
                    acc[m][n] = __builtin_amdgcn_mfma_f32_16x16x32_bf16(
                            af[m][k], bfr[n][k], acc[m][n], 0, 0, 0);
        __builtin_amdgcn_s_setprio(0);
        __builtin_amdgcn_s_barrier();   // all waves' reads of buf b complete

        if (kt + 2 < NT) STAGE(kt + 2, bA, bB);
    }

    // epilogue: D col = lane&15, row = (lane>>4)*4 + r
#pragma unroll
    for (int m = 0; m < 4; ++m) {
        long row = rowA + wm * 64 + m * 16 + g * 4;
#pragma unroll
        for (int n = 0; n < 2; ++n) {
            long col = rowB + wn * 32 + n * 16 + q16;
            f32x4 v = acc[m][n];
#pragma unroll
            for (int r = 0; r < 4; ++r)
                cstore(&C[(row + r) * (long)N + col], v[r]);
        }
    }
}

// ---------------------------------------------------------------------------
// Fused post-gemm1 kernel: ONE launch doing three independent jobs:
//   blocks [0, 2048):        wo f32->bf16 convert (grid-stride)
//   blocks [2048, 12288):    RMSNorm+RoPE
//   blocks [12288, 12800):   V transpose
// ---------------------------------------------------------------------------
__global__ __launch_bounds__(256) void post_gemm1_fused(
        const float* __restrict__ wo, short* __restrict__ wob,
        const short* __restrict__ qkvb, const int* __restrict__ pos,
        const float* __restrict__ gq, const float* __restrict__ gk,
        short* __restrict__ qo, short* __restrict__ ko,
        short* __restrict__ vt)
{
    const int bid = blockIdx.x;

    if (bid < 2048) {
        // ---- wo f32 -> bf16 convert ----
        const long n = (long)HID * (NH * DH);
        long i0 = ((long)bid * 256 + threadIdx.x) * 4;
        long stride = 2048L * 256 * 4;
        for (long i = i0; i < n; i += stride) {
            float4 v = *(const float4*)(wo + i);
            s16x4 o;
            o[0] = f2bf(v.x); o[1] = f2bf(v.y); o[2] = f2bf(v.z); o[3] = f2bf(v.w);
            *(s16x4*)(wob + i) = o;
        }
        return;
    }

    if (bid < 12288) {
        // ---- RMSNorm + RoPE ----
        const int idx = bid - 2048;
        const int s = idx / 5;
        const int slot = (idx % 5) * 8 + (threadIdx.x >> 5);   // 0..39
        const int p = threadIdx.x & 31, d = p * 4;

        s16x4 xv = *(const s16x4*)(qkvb + (long)s * NQKV + slot * DH + d);
        float x[4];
#pragma unroll
        for (int r = 0; r < 4; ++r) x[r] = bf2f(xv[r]);

        float ss = x[0]*x[0] + x[1]*x[1] + x[2]*x[2] + x[3]*x[3];
#pragma unroll
        for (int o = 1; o < 32; o <<= 1) ss += __shfl_xor(ss, o);
        float rms = rsqrtf(ss * (1.0f / DH) + 1e-6f);

        const bool isq = slot < NH;
        const float* gp = isq ? gq : gk;
        float y[4];
#pragma unroll
        for (int r = 0; r < 4; ++r) y[r] = x[r] * rms * gp[d + r];

        float y2[4];
#pragma unroll
        for (int r = 0; r < 4; ++r) y2[r] = __shfl_xor(y[r], 16);

        const float po = (float)pos[s];
        const int jbase = d & 63;
        s16x4 ov;
#pragma unroll
        for (int r = 0; r < 4; ++r) {
            float invf = exp2f(-(float)(jbase + r) * (13.287712379549449f / 64.0f));
            float ang = po * invf;
            float c = cosf(ang), sn = sinf(ang);
            float outv = (d < 64) ? (y[r] * c - y2[r] * sn)
                                  : (y[r] * c + y2[r] * sn);
            ov[r] = f2bf(outv);
        }
        if (isq) *(s16x4*)(qo + ((long)s * NH + slot) * DH + d) = ov;
        else     *(s16x4*)(ko + ((long)s * NKV + (slot - NH)) * DH + d) = ov;
        return;
    }

    // ---- V transpose: qkvb v-slots -> vt[h][d][s], 64x64 LDS tiles ----
    __shared__ short tile[64][72];
    const int idx2 = bid - 12288;
    const int sb = idx2 & 31, db = (idx2 >> 5) & 1, h = idx2 >> 6;
    const int t = threadIdx.x;
#pragma unroll
    for (int i = 0; i < 2; ++i) {
        int c = i * 256 + t;
        int row = c >> 3, dc = (c & 7) * 8;
        const short* src = qkvb + (long)(sb*64 + row) * NQKV
                           + (NH + NKV + h) * DH + db*64 + dc;
        s16x8 x = *(const s16x8*)src;
#pragma unroll
        for (int jj = 0; jj < 8; ++jj) tile[row][dc + jj] = x[jj];
    }
    __syncthreads();
#pragma unroll
    for (int i = 0; i < 2; ++i) {
        int c = i * 256 + t;
        int dr = c >> 3, sc = (c & 7) * 8;
        s16x8 y;
#pragma unroll
        for (int jj = 0; jj < 8; ++jj) y[jj] = tile[sc + jj][dr];
        short* dst = vt + (long)(h*DH + db*64 + dr) * S_LEN + sb*64 + sc;
        *(s16x8*)dst = y;
    }
}

// ---------------------------------------------------------------------------
// stage one K tile [64][128] and one Vt tile [128][64] into LDS via
// global_load_lds, PRE-SWIZZLED global source (+ linear LDS dest).
// V staging is PREFETCH (fire-and-forget DMA a tile ahead) — r18's
// V-from-global inline gather was 3x slower (latency-serialized).
// ---------------------------------------------------------------------------
__device__ __forceinline__ void stage_kv(const char* kgB, const char* vgB,
                                         int kt, int t, char* kd, char* vd)
{
    const int w = t >> 6;
#pragma unroll
    for (int ci = 0; ci < 4; ++ci) {
        int c = ci * 256 + t;
        int row = c >> 4, col16 = c & 15;
        const char* gk = kgB + (long)(kt*64 + row) * (NKV*DH*2)
                         + ((col16*16) ^ ((row & 7) << 4));
        gload16(gk, kd + ci*4096 + w*1024);
        int rowv = c >> 3, scol8 = c & 7;
        const char* gv = vgB + (long)rowv * (S_LEN*2) + kt*128
                         + ((scol8*16) ^ ((rowv & 7) << 4));
        gload16(gv, vd + ci*4096 + w*1024);
    }
}

// ---------------------------------------------------------------------------
// Causal GQA flash attention, v12 (round-8 math, co-residency grid) — the
// best-measured variant (r14/r16/r17). r18's V-from-global reverted.
// ---------------------------------------------------------------------------
__global__ __launch_bounds__(256, 2) void attn_kernel(
        const short* __restrict__ qg, const short* __restrict__ kg,
        const short* __restrict__ vtg, short* __restrict__ ctx)
{
    const int bx = blockIdx.x;       // 0..511
    const int h  = bx & 31;          // head
    const int slot = bx >> 5;        // 0..15
    const int qb = (slot < 8) ? slot : 23 - slot;   // complementary pairing
    const int kvh = h >> 2;          // GQA: rep=4
    const int t = threadIdx.x, w = t >> 6, l = t & 63, g = l >> 4, q16 = l & 15;

    __shared__ char Kl[2][16384];    // [kv64][d128] bf16, swizzled
    __shared__ char Vl[2][16384];    // [d128][kv64] bf16, swizzled
    __shared__ short Pl[4][32 * 64]; // per-wave P[32 q][64 kv], swizzled

    const float scale = 0.08838834764831845f;  // 1/sqrt(128)
    const char* kgB = (const char*)kg + (long)kvh * DH * 2;
    const char* vgB = (const char*)vtg + (long)kvh * DH * (long)S_LEN * 2;

    const int nt = 2 * qb + 2;               // kv-tiles of 64
    int qrow[2];
    qrow[0] = qb*128 + w*32 + q16;
    qrow[1] = qrow[0] + 16;

    // Q B-frags for both subtiles (regs for whole block)
    s16x8 qf[2][4];
#pragma unroll
    for (int s = 0; s < 2; ++s) {
        const short* qptr = qg + ((long)qrow[s] * NH + h) * DH;
#pragma unroll
        for (int dk = 0; dk < 4; ++dk)
            qf[s][dk] = *(const s16x8*)(qptr + dk*32 + g*8);
    }

    f32x4 oacc[2][8] = {};
    float m_run[2] = {-1e30f, -1e30f}, l_run[2] = {0.f, 0.f};

    stage_kv(kgB, vgB, 0, t, Kl[0], Vl[0]);
    __syncthreads();   // drain vmcnt -> buf0 ready

    for (int kt = 0; kt < nt; ++kt) {
        const int b = kt & 1;
        if (kt + 1 < nt)   // prefetch next tile into other buffer (async)
            stage_kv(kgB, vgB, kt + 1, t, Kl[b ^ 1], Vl[b ^ 1]);
        const char* kb = Kl[b];
        const char* vbb = Vl[b];

        // ---- QK^T swapped: S^T[kv][q] = K * Q^T; K-frags serve both s
        f32x4 sacc[2][4] = {};
        __builtin_amdgcn_s_setprio(1);
#pragma unroll
        for (int m = 0; m < 4; ++m) {
            int kvr = m*16 + q16;
            s16x8 af[4];
#pragma unroll
            for (int dk = 0; dk < 4; ++dk) {
                int byte = (kvr*256 + (dk*32 + g*8)*2) ^ ((kvr & 7) << 4);
                af[dk] = *(const s16x8*)(kb + byte);
            }
#pragma unroll
            for (int s = 0; s < 2; ++s)
#pragma unroll
                for (int dk = 0; dk < 4; ++dk)
                    sacc[s][m] = __builtin_amdgcn_mfma_f32_16x16x32_bf16(
                            af[dk], qf[s][dk], sacc[s][m], 0,0,0);
        }
        __builtin_amdgcn_s_setprio(0);

        // ---- online softmax; lane owns q-columns qrow[0], qrow[1] ----
        const bool diag = (kt >= 2*qb);      // last two tiles straddle diag
        float mx[2];
#pragma unroll
        for (int s = 0; s < 2; ++s) {
            mx[s] = -1e30f;
#pragma unroll
            for (int m = 0; m < 4; ++m)
#pragma unroll
                for (int r = 0; r < 4; ++r) {
                    float x = sacc[s][m][r] * scale;
                    if (diag) {
                        int kv = kt*64 + m*16 + g*4 + r;
                        if (kv > qrow[s]) x = -1e30f;
                    }
                    sacc[s][m][r] = x;
                    mx[s] = fmaxf(mx[s], x);
                }
            mx[s] = fmaxf(mx[s], __shfl_xor(mx[s], 16));
            mx[s] = fmaxf(mx[s], __shfl_xor(mx[s], 32));
        }
        // defer-max: only rescale when max grew by > 8 somewhere (T13)
        if (__any((mx[0] > m_run[0] + 8.f) || (mx[1] > m_run[1] + 8.f))) {
#pragma unroll
            for (int s = 0; s < 2; ++s) {
                float m_new = fmaxf(m_run[s], mx[s]);
                float corr = __expf(m_run[s] - m_new);
                l_run[s] *= corr;
                m_run[s] = m_new;
                float rf[4];
#pragma unroll
                for (int r = 0; r < 4; ++r)
                    rf[r] = __shfl(corr, (g << 4) | (g*4 + r));
#pragma unroll
                for (int nf = 0; nf < 8; ++nf)
#pragma unroll
                    for (int r = 0; r < 4; ++r) oacc[s][nf][r] *= rf[r];
            }
        }
        // exp + pack to bf16 + LDS write (P bounded by e^8 when deferred)
#pragma unroll
        for (int s = 0; s < 2; ++s) {
            float psum = 0.f;
#pragma unroll
            for (int m = 0; m < 4; ++m) {
                s16x4 pk;
#pragma unroll
                for (int r = 0; r < 4; ++r) {
                    float e = __expf(sacc[s][m][r] - m_run[s]);
                    psum += e;
                    pk[r] = f2bf(e);
                }
                int byte = ((s*16 + q16)*128 + (m*16 + g*4)*2) ^ ((q16 & 7) << 4);
                *(s16x4*)((char*)&Pl[w][0] + byte) = pk;
            }
            psum += __shfl_xor(psum, 16);
            psum += __shfl_xor(psum, 32);
            l_run[s] += psum;
        }

        // ---- PV: O[q][d] += P[q][kv] * V[kv][d]; V-frags serve both s
        __builtin_amdgcn_s_setprio(1);
#pragma unroll
        for (int ks = 0; ks < 2; ++ks) {
            s16x8 pa[2];
#pragma unroll
            for (int s = 0; s < 2; ++s) {
                int pbyte = ((s*16 + q16)*128 + (ks*32 + g*8)*2) ^ ((q16 & 7) << 4);
                pa[s] = *(const s16x8*)((const char*)&Pl[w][0] + pbyte);
            }
#pragma unroll
            for (int nf = 0; nf < 8; ++nf) {
                int drow = nf*16 + q16;
                int vbyte = (drow*128 + (ks*32 + g*8)*2) ^ ((drow & 7) << 4);
                s16x8 vbf = *(const s16x8*)(vbb + vbyte);
#pragma unroll
                for (int s = 0; s < 2; ++s)
                    oacc[s][nf] = __builtin_amdgcn_mfma_f32_16x16x32_bf16(
                            pa[s], vbf, oacc[s][nf], 0,0,0);
            }
        }
        __builtin_amdgcn_s_setprio(0);
        __syncthreads();   // tile done; prefetched buffer complete
    }

    // ---- epilogue: divide by l, write ctx[row][h*128 + d] bf16 ----
#pragma unroll
    for (int s = 0; s < 2; ++s) {
        float lr[4];
#pragma unroll
        for (int r = 0; r < 4; ++r)
            lr[r] = __shfl(l_run[s], (g << 4) | (g*4 + r));
#pragma unroll
        for (int nf = 0; nf < 8; ++nf)
#pragma unroll
            for (int r = 0; r < 4; ++r) {
                int row = qb*128 + w*32 + s*16 + g*4 + r;
                int col = h*DH + nf*16 + q16;
                float val = oacc[s][nf][r] / lr[r];
                ctx[(long)row * (NH*DH) + col] = f2bf(val);
            }
    }
}

// ---------------------------------------------------------------------------
// Workspace layout (race-free, peak 111 MB):
//   [0,16)    hsb (gemm1 A)           -> ctxb (attn out) after gemm1
//   [16,67)   wqkvb (gemm1 B, 50.3MB) -> wob (32MB) after gemm1
//   [48,52)   vtbuf (4MB, written after gemm1)
//   [67,91)   qkvb (gemm1 bf16 out, 24MB)
//   [91,107)  qbuf (16MB)
//   [107,111) kbuf (4MB)
// ---------------------------------------------------------------------------
extern "C" void kernel_launch(void* const* d_in, const int* in_sizes, int n_in,
                              void* d_out, int out_size, void* d_ws, size_t ws_size,
                              hipStream_t stream)
{
    const int*   positions = (const int*)  d_in[0];
    const float* hs        = (const float*)d_in[1];
    const float* wqkv      = (const float*)d_in[2];
    const float* wo        = (const float*)d_in[3];
    const float* gq        = (const float*)d_in[4];
    const float* gk        = (const float*)d_in[5];
    float* out = (float*)d_out;
    char* ws = (char*)d_ws;

    const size_t MB = 1ull << 20;
    short* hsb   = (short*)(ws);
    short* ctxb  = (short*)(ws);
    short* wqkvb = (short*)(ws + 16*MB);
    short* wob   = (short*)(ws + 16*MB);
    short* vtbuf = (short*)(ws + 48*MB);
    short* qkvb  = (short*)(ws + 67*MB);
    short* qbuf  = (short*)(ws + 91*MB);
    short* kbuf  = (short*)(ws + 107*MB);

    (void)in_sizes; (void)n_in; (void)out_size; (void)ws_size;

    convert_hs_wqkv<<<2048, 256, 0, stream>>>(
            hs, hsb, (long)S_LEN * HID,
            wqkv, wqkvb, (long)NQKV * HID);
    gemm192<short><<<dim3(NQKV/192, S_LEN/256), 512, 0, stream>>>(
            hsb, wqkvb, qkvb, S_LEN, NQKV, HID);
    post_gemm1_fused<<<12800, 256, 0, stream>>>(
            wo, wob, qkvb, positions, gq, gk, qbuf, kbuf, vtbuf);
    attn_kernel<<<dim3(512), 256, 0, stream>>>(qbuf, kbuf, vtbuf, ctxb);
    gemm_bt<float><<<dim3(HID/128, S_LEN/128), 512, 0, stream>>>(
            ctxb, wob, out, S_LEN, HID, HID);
}